// Round 11
// baseline (66.464 us; speedup 1.0000x reference)
//
#include <hip/hip_runtime.h>
#include <math.h>

// SSIM char-matcher: img (1,1,1024,768) f32, chars (95,1,16,6) f32 -> argmax idx [64][128] int32
// H=16, W=6, WIN=3, tiles T=8192 (64 rows x 128 cols), refs R=95 (pad to 96)
//
// R11 structure: px-split. Grid 512 = 64 rows x 4 colgroups x 2 PIXEL-halves.
// Block: 384 threads = 6 waves; block covers 32 tiles x 96 refs x 48 px
// (its half of the 96 pixels); wave owns 8 px, thread = 8 tiles x 6 refs.
// Wave-private double-buffered ref chunks (no main-loop barriers, counted
// vmcnt). LDS 77.8 KB -> 2 blocks/CU -> 3 waves/SIMD (vs R7's 2, which left
// VALUBusy at 55%). Partial scores+density -> scratch; combine kernel sums,
// applies density penalty, argmax. Fallback to the proven single-kernel R7
// path if ws_size can't hold the 6.8 MB scratch.

static constexpr float kC1 = 1.0e-4f;   // 0.01^2
static constexpr float kC2 = 9.0e-4f;   // 0.03^2

struct KF { float k[9]; };

__device__ __forceinline__ int refl(int x, int n) {
  if (x < 0) return -x;
  if (x >= n) return 2 * n - 2 - x;
  return x;
}

// ---------------- Kernel 1: per-ref precompute ----------------
// refdata: per hw a chunk of 96 rows x 12 floats (4608 B, contiguous).
// Logical ref r stored at physical row rp = r/6 + 16*(r%6): lane rthr reads
// ref rthr*6+j at row rthr+16j (stride 48 B, 2-way banks = ~free).
// Row: f0..8 = 2*k[k]*Rp[k], f9 = 2*mu_r, f10 = mu_r^2+C1, f11 = sig_r+C2.
// r=95 is padding (never argmax'd).
__global__ __launch_bounds__(128) void refprep_kernel(
    const float* __restrict__ chars, float* __restrict__ refdata,
    float* __restrict__ densR, KF kf) {
  const int hw = blockIdx.x;   // 0..95
  const int r = threadIdx.x;   // 0..127
  if (r >= 96) return;
  const int rp = r / 6 + 16 * (r % 6);
  float* row = refdata + ((size_t)hw * 96 + rp) * 12;
  const int h = hw / 6, w = hw % 6;
  if (r < 95) {
    const float* cb = chars + r * 96;
    float mu = 0.f, ex2 = 0.f;
    float wrv[9];
#pragma unroll
    for (int i = 0; i < 3; ++i) {
      const int hh = refl(h + i - 1, 16);
#pragma unroll
      for (int j = 0; j < 3; ++j) {
        const int ww = refl(w + j - 1, 6);
        const float p = cb[hh * 6 + ww];
        const float kv = kf.k[i * 3 + j];
        wrv[i * 3 + j] = 2.0f * kv * p;
        mu += kv * p;
        ex2 += kv * p * p;
      }
    }
    const float sig = ex2 - mu * mu;
#pragma unroll
    for (int k = 0; k < 9; ++k) row[k] = wrv[k];
    row[9]  = 2.0f * mu;
    row[10] = mu * mu + kC1;
    row[11] = sig + kC2;
  } else {
#pragma unroll
    for (int k = 0; k < 9; ++k) row[k] = 0.f;
    row[9]  = 0.f;
    row[10] = kC1;
    row[11] = kC2;
  }
  if (hw == 0) {
    if (r < 95) {
      float s = 0.f;
      for (int i = 0; i < 96; ++i) s += chars[r * 96 + i];
      densR[r] = s * (1.0f / 96.0f);
    } else {
      densR[r] = 0.f;
    }
  }
}

// ---- async global->LDS staging of one 1152-float (4608 B) ref chunk ----
// 4 x (64 lanes x 16B) + 2 x (64 lanes x 4B); counts 6 on vmcnt.
__device__ __forceinline__ void stage_px(const float* __restrict__ src,
                                         float* dst, int lane) {
  const uintptr_t gs = (uintptr_t)src;
  const uintptr_t ls = (uintptr_t)dst;
#define G_(off) ((const __attribute__((address_space(1))) void*)(gs + (off)))
#define L_(off) ((__attribute__((address_space(3))) void*)(uint32_t)(ls + (off)))
  __builtin_amdgcn_global_load_lds(G_(0    + lane * 16), L_(0),    16, 0, 0);
  __builtin_amdgcn_global_load_lds(G_(1024 + lane * 16), L_(1024), 16, 0, 0);
  __builtin_amdgcn_global_load_lds(G_(2048 + lane * 16), L_(2048), 16, 0, 0);
  __builtin_amdgcn_global_load_lds(G_(3072 + lane * 16), L_(3072), 16, 0, 0);
  __builtin_amdgcn_global_load_lds(G_(4096 + lane * 4),  L_(4096), 4, 0, 0);
  __builtin_amdgcn_global_load_lds(G_(4352 + lane * 4),  L_(4352), 4, 0, 0);
#undef G_
#undef L_
}

// ---------------- Kernel 2a: main SSIM, px-split half ----------------
// 512 blocks x 384 threads (6 waves). Block = 32 tiles x 96 refs x 48 px.
// Wave w: px [8w, 8w+8) of this half. lane = tthr(4 x 8 tiles) x rthr(16 x
// 6 refs) -> 48 el/thread-px. Outputs partial score sums [96 ref][32 tile]
// and partial tile-density sums to scratch.
// __launch_bounds__(384,2): min=2 keeps the allocator pressure-driven
// (R2/R7/R10 evidence: only (.,2) avoids the squeeze-to-tier spills).
__global__ __launch_bounds__(384, 2)
void ssim_half_kernel(
    const float* __restrict__ img, const float* __restrict__ refdata,
    float* __restrict__ part, float* __restrict__ densP, KF kf) {
  // floats: [0:2560) padT [10 rows][8 pcols][32 tiles] (this half's rows)
  //         [2560:5632) statT [2][48][32]
  //         [5632:19456) refbuf 6 waves x 2 x 1152
  // Overlay after main loop: sb[6][32][97] = 18624 floats.
  __shared__ float smem[19456];
  float* padT = smem;
  float* statT = smem + 2560;

  const int tid = threadIdx.x;
  const int w = tid >> 6;          // wave 0..5
  const int lane = tid & 63;
  const int tthr = lane >> 4;      // 0..3  -> 8 tiles each
  const int rthr = lane & 15;      // 0..15 -> 6 refs each
  const int tl0 = tthr * 8;
  const int blk = blockIdx.x;
  const int row0 = blk >> 3;           // tile-row 0..63
  const int colg = (blk >> 1) & 3;
  const int half = blk & 1;            // pixel half: rows [8h, 8h+8)
  const int c0 = colg * 32;
  const int bxy = row0 * 4 + colg;     // 0..255
  const int trb = half * 8;            // tile-row base of this half
  const int hwBase = half * 48 + w * 8;  // global first px of this wave
  float* rbuf = smem + 5632 + w * 2304;  // wave-private 2 x 1152

  // Issue px0 staging immediately; the first __syncthreads drains it.
  stage_px(refdata + (size_t)hwBase * 1152, rbuf, lane);

  // Phase A: reflect-padded tile rows trb-1..trb+8, transposed:
  // padT[(pr*8+pw)*32 + tl], pr 0..9, pw 0..7.
  for (int idx = tid; idx < 2560; idx += 384) {
    const int c = idx >> 5, tl = idx & 31;
    const int pr = c >> 3, pw = c & 7;
    const int h = refl(trb + pr - 1, 16), ww = refl(pw - 1, 6);
    padT[idx] = img[(row0 * 16 + h) * 768 + (c0 + tl) * 6 + ww];
  }
  __syncthreads();

  // Partial tile-density (this half's 8 rows x 6 cols), straight to scratch.
  if (tid < 32) {
    float s = 0.f;
    for (int pr = 1; pr <= 8; ++pr)
      for (int pw = 1; pw <= 6; ++pw)
        s += padT[(pr * 8 + pw) * 32 + tid];
    densP[half * 8192 + row0 * 128 + c0 + tid] = s;   // raw sum (no /96)
  }
  // Phase B: per-(hw_local, tile) stats: mu, sig  (48 local px)
  for (int idx = tid; idx < 1536; idx += 384) {
    const int hwl = idx >> 5, tl = idx & 31;
    const int hl = hwl / 6, w6l = hwl % 6;
    float mu = 0.f, ex2 = 0.f;
#pragma unroll
    for (int i = 0; i < 3; ++i)
#pragma unroll
      for (int j = 0; j < 3; ++j) {
        const float p = padT[((hl + i) * 8 + (w6l + j)) * 32 + tl];
        const float kv = kf.k[i * 3 + j];
        mu += kv * p;
        ex2 += kv * p * p;
      }
    statT[idx] = mu;
    statT[1536 + idx] = ex2 - mu * mu;
  }
  __syncthreads();   // also drains prologue staging (vmcnt(0) before barrier)

  float score[8][6];
#pragma unroll
  for (int i = 0; i < 8; ++i)
#pragma unroll
    for (int j = 0; j < 6; ++j) score[i][j] = 0.f;

  // Incremental addressing; wave may start mid-row.
  int w6 = (w * 8) % 6;
  int pb = ((w * 8) / 6 * 8 + w6) * 32 + tl0;   // padT window-origin offset
  int sbase = (w * 8) * 32 + tl0;               // statT offset (local hw)
  const float* refsrc = refdata + (size_t)(hwBase + 1) * 1152;

#pragma unroll 1
  for (int it = 0; it < 8; ++it) {
    const float* buf = rbuf + (it & 1) * 1152;

    if (it < 7) {
      // Restaged buffer's last ds_reads were consumed in it-1 -> WAR-safe.
      // Counted vmcnt: this px's 6 loads complete, next px's 6 in flight.
      stage_px(refsrc, rbuf + ((it + 1) & 1) * 1152, lane);
      asm volatile("s_waitcnt vmcnt(6)" ::: "memory");
    } else {
      asm volatile("s_waitcnt vmcnt(0)" ::: "memory");
    }
    refsrc += 1152;

    // Tile window pixels: 9 taps x 8 tiles (18 x ds_read_b128)
    float tp[9][8];
#pragma unroll
    for (int ik = 0; ik < 3; ++ik)
#pragma unroll
      for (int jk = 0; jk < 3; ++jk) {
        const int k = ik * 3 + jk;
        const float4 a = *(const float4*)&padT[pb + (ik * 8 + jk) * 32];
        const float4 b = *(const float4*)&padT[pb + (ik * 8 + jk) * 32 + 4];
        tp[k][0] = a.x; tp[k][1] = a.y; tp[k][2] = a.z; tp[k][3] = a.w;
        tp[k][4] = b.x; tp[k][5] = b.y; tp[k][6] = b.z; tp[k][7] = b.w;
      }

    // tile stats (8 tiles): mu, sig
    float mu[8], sg[8], mt2[8];
    {
      float4 v;
      v = *(const float4*)&statT[sbase];            mu[0]=v.x; mu[1]=v.y; mu[2]=v.z; mu[3]=v.w;
      v = *(const float4*)&statT[sbase + 4];        mu[4]=v.x; mu[5]=v.y; mu[6]=v.z; mu[7]=v.w;
      v = *(const float4*)&statT[1536 + sbase];     sg[0]=v.x; sg[1]=v.y; sg[2]=v.z; sg[3]=v.w;
      v = *(const float4*)&statT[1536 + sbase + 4]; sg[4]=v.x; sg[5]=v.y; sg[6]=v.z; sg[7]=v.w;
#pragma unroll
      for (int i = 0; i < 8; ++i) mt2[i] = mu[i] * mu[i];
    }

#pragma unroll
    for (int j = 0; j < 6; ++j) {
      const int rb = (rthr + 16 * j) * 12;
      const float4 wa = *(const float4*)&buf[rb];
      const float4 wb = *(const float4*)&buf[rb + 4];
      const float4 wc = *(const float4*)&buf[rb + 8];
#pragma unroll
      for (int i = 0; i < 8; ++i) {
        float ev = fmaf(tp[0][i], wa.x, kC2);
        ev = fmaf(tp[1][i], wa.y, ev);
        ev = fmaf(tp[2][i], wa.z, ev);
        ev = fmaf(tp[3][i], wa.w, ev);
        ev = fmaf(tp[4][i], wb.x, ev);
        ev = fmaf(tp[5][i], wb.y, ev);
        ev = fmaf(tp[6][i], wb.z, ev);
        ev = fmaf(tp[7][i], wb.w, ev);
        ev = fmaf(tp[8][i], wc.x, ev);
        // wc.y = 2*mu_r, wc.z = mu_r^2+C1, wc.w = sig_r+C2
        const float am = mu[i] * wc.y;             // 2*mt*mr
        const float n1 = am + kC1;
        const float n2 = ev - am;                  // 2*sig_tr + C2
        const float d1 = mt2[i] + wc.z;            // mt^2+mr^2+C1
        const float d2 = sg[i] + wc.w;
        const float nn = n1 * n2;
        const float dd = d1 * d2;
        // raw v_rcp_f32: ~1-ulp (passed absmax 0 since R8).
        const float r0v = __builtin_amdgcn_rcpf(dd);
        score[i][j] = fmaf(nn, r0v, score[i][j]);
      }
    }

    pb += (w6 == 5) ? 96 : 32;       // col step 32; row wrap: +3 window cols
    w6 = (w6 == 5) ? 0 : w6 + 1;
    sbase += 32;
  }

  // Overlay sb[6][32][97] over all of smem: barrier first (all waves done).
  __syncthreads();
  float* sb = smem;
#pragma unroll
  for (int i = 0; i < 8; ++i)
#pragma unroll
    for (int j = 0; j < 6; ++j)
      sb[w * 3104 + (tl0 + i) * 97 + (rthr * 6 + j)] = score[i][j];
  __syncthreads();

  // Reduce 6 wave-partials -> part[half][bxy][96 ref][32 tile]
  {
    const int r = tid >> 2;          // 0..95
    const int tq = tid & 3;          // 8 tiles each
    float* dst = part + (((size_t)(half * 256 + bxy) * 96 + r) * 32 + tq * 8);
#pragma unroll
    for (int t = 0; t < 8; ++t) {
      const int tile = tq * 8 + t;
      float s = 0.f;
#pragma unroll
      for (int g = 0; g < 6; ++g) s += sb[g * 3104 + tile * 97 + r];
      dst[t] = s;
    }
  }
}

// ---------------- Kernel 2b: combine halves + density + argmax ----------------
__global__ __launch_bounds__(512) void combine_kernel(
    const float* __restrict__ part, const float* __restrict__ densP,
    const float* __restrict__ densR, int* __restrict__ out) {
  __shared__ float sb2[32 * 97];
  __shared__ float sdens[32];
  const int tid = threadIdx.x;
  const int bxy = blockIdx.x;          // 0..255
  const float* p0 = part + (size_t)bxy * 3072;
  const float* p1 = part + (size_t)(256 + bxy) * 3072;

  for (int idx = tid; idx < 3072; idx += 512) {
    const int r = idx >> 5, t = idx & 31;
    sb2[t * 97 + r] = p0[idx] + p1[idx];
  }
  if (tid < 32) {
    const int g = (bxy >> 2) * 128 + (bxy & 3) * 32 + tid;
    sdens[tid] = (densP[g] + densP[8192 + g]) * (1.0f / 96.0f);
  }
  __syncthreads();

  const int tile = tid >> 4, rt = tid & 15;
  const float dt = sdens[tile];
  float best = -1e30f; int bi = 0;
#pragma unroll
  for (int q = 0; q < 6; ++q) {
    const int r = rt * 6 + q;
    if (r < 95) {
      float s = sb2[tile * 97 + r] * (1.0f / 96.0f)
              - 3.0f * fabsf(dt - densR[r]);
      if (s > best) { best = s; bi = r; }   // ascending r, strict >
    }
  }
#pragma unroll
  for (int m = 8; m >= 1; m >>= 1) {
    const float ob = __shfl_xor(best, m, 64);
    const int oi = __shfl_xor(bi, m, 64);
    if (ob > best || (ob == best && oi < bi)) { best = ob; bi = oi; }
  }
  if (rt == 0) {
    const int g = (bxy >> 2) * 128 + (bxy & 3) * 32 + tile;
    out[g] = bi;
  }
}

// ---------------- Fallback: proven R7 single-kernel path (50 us) ----------------
__global__ __launch_bounds__(512, 2)
void ssim_full_kernel(
    const float* __restrict__ img, const float* __restrict__ refdata,
    const float* __restrict__ densR, int* __restrict__ out, KF kf) {
  __shared__ float smem[29184];
  __shared__ float densT[32];
  float* padT = smem;
  float* statT = smem + 4608;

  const int tid = threadIdx.x;
  const int w = tid >> 6;
  const int lane = tid & 63;
  const int tthr = lane >> 4;
  const int rthr = lane & 15;
  const int tl0 = tthr * 8;
  const int blk = blockIdx.x;
  const int row0 = blk >> 2;
  const int c0 = (blk & 3) * 32;
  const int hwBase = w * 12;
  float* rbuf = smem + 10752 + w * 2304;

  stage_px(refdata + (size_t)hwBase * 1152, rbuf, lane);

  for (int idx = tid; idx < 4608; idx += 512) {
    const int c = idx >> 5, tl = idx & 31;
    const int ph = c >> 3, pw = c & 7;
    const int h = refl(ph - 1, 16), ww = refl(pw - 1, 6);
    padT[idx] = img[(row0 * 16 + h) * 768 + (c0 + tl) * 6 + ww];
  }
  __syncthreads();

  if (tid < 32) {
    float s = 0.f;
    for (int h = 0; h < 16; ++h)
      for (int ww = 0; ww < 6; ++ww)
        s += padT[((h + 1) * 8 + (ww + 1)) * 32 + tid];
    densT[tid] = s * (1.0f / 96.0f);
  }
  for (int idx = tid; idx < 3072; idx += 512) {
    const int hw = idx >> 5, tl = idx & 31;
    const int h = hw / 6, ww = hw % 6;
    float mu = 0.f, ex2 = 0.f;
#pragma unroll
    for (int i = 0; i < 3; ++i)
#pragma unroll
      for (int j = 0; j < 3; ++j) {
        const float p = padT[((h + i) * 8 + (ww + j)) * 32 + tl];
        const float kv = kf.k[i * 3 + j];
        mu += kv * p;
        ex2 += kv * p * p;
      }
    statT[idx] = mu;
    statT[3072 + idx] = ex2 - mu * mu;
  }
  __syncthreads();

  float score[8][6];
#pragma unroll
  for (int i = 0; i < 8; ++i)
#pragma unroll
    for (int j = 0; j < 6; ++j) score[i][j] = 0.f;

  int w6 = 0;
  int pb = (2 * w) * 8 * 32 + tl0;
  int sbase = hwBase * 32 + tl0;
  const float* refsrc = refdata + (size_t)(hwBase + 1) * 1152;

#pragma unroll 1
  for (int it = 0; it < 12; ++it) {
    const float* buf = rbuf + (it & 1) * 1152;
    if (it < 11) {
      stage_px(refsrc, rbuf + ((it + 1) & 1) * 1152, lane);
      asm volatile("s_waitcnt vmcnt(6)" ::: "memory");
    } else {
      asm volatile("s_waitcnt vmcnt(0)" ::: "memory");
    }
    refsrc += 1152;

    float tp[9][8];
#pragma unroll
    for (int ik = 0; ik < 3; ++ik)
#pragma unroll
      for (int jk = 0; jk < 3; ++jk) {
        const int k = ik * 3 + jk;
        const float4 a = *(const float4*)&padT[pb + (ik * 8 + jk) * 32];
        const float4 b = *(const float4*)&padT[pb + (ik * 8 + jk) * 32 + 4];
        tp[k][0] = a.x; tp[k][1] = a.y; tp[k][2] = a.z; tp[k][3] = a.w;
        tp[k][4] = b.x; tp[k][5] = b.y; tp[k][6] = b.z; tp[k][7] = b.w;
      }
    float mu[8], sg[8], mt2[8];
    {
      float4 v;
      v = *(const float4*)&statT[sbase];            mu[0]=v.x; mu[1]=v.y; mu[2]=v.z; mu[3]=v.w;
      v = *(const float4*)&statT[sbase + 4];        mu[4]=v.x; mu[5]=v.y; mu[6]=v.z; mu[7]=v.w;
      v = *(const float4*)&statT[3072 + sbase];     sg[0]=v.x; sg[1]=v.y; sg[2]=v.z; sg[3]=v.w;
      v = *(const float4*)&statT[3072 + sbase + 4]; sg[4]=v.x; sg[5]=v.y; sg[6]=v.z; sg[7]=v.w;
#pragma unroll
      for (int i = 0; i < 8; ++i) mt2[i] = mu[i] * mu[i];
    }
#pragma unroll
    for (int j = 0; j < 6; ++j) {
      const int rb = (rthr + 16 * j) * 12;
      const float4 wa = *(const float4*)&buf[rb];
      const float4 wb = *(const float4*)&buf[rb + 4];
      const float4 wc = *(const float4*)&buf[rb + 8];
#pragma unroll
      for (int i = 0; i < 8; ++i) {
        float ev = fmaf(tp[0][i], wa.x, kC2);
        ev = fmaf(tp[1][i], wa.y, ev);
        ev = fmaf(tp[2][i], wa.z, ev);
        ev = fmaf(tp[3][i], wa.w, ev);
        ev = fmaf(tp[4][i], wb.x, ev);
        ev = fmaf(tp[5][i], wb.y, ev);
        ev = fmaf(tp[6][i], wb.z, ev);
        ev = fmaf(tp[7][i], wb.w, ev);
        ev = fmaf(tp[8][i], wc.x, ev);
        const float am = mu[i] * wc.y;
        const float n1 = am + kC1;
        const float n2 = ev - am;
        const float d1 = mt2[i] + wc.z;
        const float d2 = sg[i] + wc.w;
        const float nn = n1 * n2;
        const float dd = d1 * d2;
        const float r0v = __builtin_amdgcn_rcpf(dd);
        score[i][j] = fmaf(nn, r0v, score[i][j]);
      }
    }
    pb += (w6 == 5) ? 96 : 32;
    w6 = (w6 == 5) ? 0 : w6 + 1;
    sbase += 32;
  }

  __syncthreads();
  float* sb = smem;
#pragma unroll
  for (int i = 0; i < 8; ++i)
#pragma unroll
    for (int j = 0; j < 6; ++j)
      sb[w * 3104 + (tl0 + i) * 97 + (rthr * 6 + j)] = score[i][j];
  __syncthreads();

  {
    const int tile = tid >> 4, rt = tid & 15;
    const float dt = densT[tile];
    float best = -1e30f; int bi = 0;
#pragma unroll
    for (int q = 0; q < 6; ++q) {
      const int r = rt * 6 + q;
      if (r < 95) {
        float s = 0.f;
#pragma unroll
        for (int g = 0; g < 8; ++g) s += sb[g * 3104 + tile * 97 + r];
        s = s * (1.0f / 96.0f) - 3.0f * fabsf(dt - densR[r]);
        if (s > best) { best = s; bi = r; }
      }
    }
#pragma unroll
    for (int m = 8; m >= 1; m >>= 1) {
      const float ob = __shfl_xor(best, m, 64);
      const int oi = __shfl_xor(bi, m, 64);
      if (ob > best || (ob == best && oi < bi)) { best = ob; bi = oi; }
    }
    if (rt == 0) out[row0 * 128 + c0 + tile] = bi;
  }
}

// ---------------- Host launch ----------------
extern "C" void kernel_launch(void* const* d_in, const int* in_sizes, int n_in,
                              void* d_out, int out_size, void* d_ws, size_t ws_size,
                              hipStream_t stream) {
  (void)in_sizes; (void)n_in; (void)out_size;
  const float* img = (const float*)d_in[0];
  const float* chars = (const float*)d_in[1];
  int* out = (int*)d_out;
  float* refdata = (float*)d_ws;                  // 110592 floats
  float* densR = refdata + 110592;                // +96
  float* part = refdata + 110688;                 // 2*256*96*32 = 1572864 floats
  float* densP = part + 1572864;                  // 2*8192 floats
  const size_t need_bytes = (size_t)(110688 + 1572864 + 16384) * 4;

  KF kf;
  {
    float gg[3], s = 0.f;
    for (int i = 0; i < 3; ++i) {
      const float c = (float)i - 1.0f;
      gg[i] = expf(-(c * c) / (2.0f * 1.5f * 1.5f));
      s += gg[i];
    }
    float gn[3];
    for (int i = 0; i < 3; ++i) gn[i] = gg[i] / s;
    float k2[9]; float ks = 0.f;
    for (int i = 0; i < 3; ++i)
      for (int j = 0; j < 3; ++j) { k2[i * 3 + j] = gn[i] * gn[j]; ks += k2[i * 3 + j]; }
    for (int k = 0; k < 9; ++k) kf.k[k] = k2[k] / ks;
  }

  hipLaunchKernelGGL(refprep_kernel, dim3(96), dim3(128), 0, stream,
                     chars, refdata, densR, kf);
  if (ws_size >= need_bytes) {
    hipLaunchKernelGGL(ssim_half_kernel, dim3(512), dim3(384), 0, stream,
                       img, refdata, part, densP, kf);
    hipLaunchKernelGGL(combine_kernel, dim3(256), dim3(512), 0, stream,
                       part, densP, densR, out);
  } else {
    hipLaunchKernelGGL(ssim_full_kernel, dim3(256), dim3(512), 0, stream,
                       img, refdata, densR, out, kf);
  }
}